// Round 1
// baseline (86878.973 us; speedup 1.0000x reference)
//
#include <hip/hip_runtime.h>
#include <hip/hip_bf16.h>

#define NL 4
#define NB 64
#define NT 512
#define NH 1024
#define N3H 3072

typedef __attribute__((ext_vector_type(8))) short short8;
typedef __attribute__((ext_vector_type(4))) float floatx4;

__device__ __forceinline__ short8 ld8(const __hip_bfloat16* p) {
  return *(const short8*)p;
}

// ---------------- prep kernels ----------------

// split weights: w_ih -> bf16 hi ; w_hh -> bf16 hi + lo
__global__ void split_w_kernel(const float* __restrict__ w_ih,
                               const float* __restrict__ w_hh,
                               __hip_bfloat16* __restrict__ wih_hi,
                               __hip_bfloat16* __restrict__ whh_hi,
                               __hip_bfloat16* __restrict__ whh_lo) {
  size_t i = (size_t)blockIdx.x * 256 + threadIdx.x;
  size_t n = (size_t)NL * N3H * NH;
  if (i >= n) return;
  wih_hi[i] = __float2bfloat16(w_ih[i]);
  float v = w_hh[i];
  __hip_bfloat16 hi = __float2bfloat16(v);
  whh_hi[i] = hi;
  whh_lo[i] = __float2bfloat16(v - __bfloat162float(hi));
}

// x (fp32) -> bf16 sequence buffer A
__global__ void split_x_kernel(const float* __restrict__ x,
                               __hip_bfloat16* __restrict__ xb) {
  size_t i = (size_t)blockIdx.x * 256 + threadIdx.x;
  size_t n = (size_t)NT * NB * NH;
  if (i >= n) return;
  xb[i] = __float2bfloat16(x[i]);
}

// h0 -> d_out (fp32 master state for all layers)
__global__ void init_out_kernel(const float* __restrict__ h0,
                                float* __restrict__ out) {
  size_t i = (size_t)blockIdx.x * 256 + threadIdx.x;
  size_t n = (size_t)NL * NB * NH;
  if (i >= n) return;
  out[i] = h0[i];
}

// h0 layer slice -> bf16 h buffer (parity 0)
__global__ void init_hbf_kernel(const float* __restrict__ h0_layer,
                                __hip_bfloat16* __restrict__ hb) {
  size_t i = (size_t)blockIdx.x * 256 + threadIdx.x;
  if (i >= (size_t)NB * NH) return;
  hb[i] = __float2bfloat16(h0_layer[i]);
}

// ---------------- GRU cell step ----------------
// grid: 64 blocks (block g owns hidden units [16g, 16g+16))
// block: 256 threads = 4 waves; wave w owns batch m-tile [16w, 16w+16)
// 3 MFMA passes over K=1024: x@Wih_hi, h@Whh_hi, h@Whh_lo (w_hh split kills
// systematic bf16 weight error that would compound over 512 recurrent steps)
__global__ __launch_bounds__(256) void gru_step_kernel(
    const __hip_bfloat16* __restrict__ seq_in,   // [T][B][H] this layer's input
    __hip_bfloat16* __restrict__ seq_out,        // [T][B][H] or null (last layer)
    const __hip_bfloat16* __restrict__ h_in,     // [B][H] bf16 h (parity t&1)
    __hip_bfloat16* __restrict__ h_out,          // [B][H] bf16 h (parity (t+1)&1)
    float* __restrict__ h_fp,                    // [B][H] fp32 master (d_out slice)
    const __hip_bfloat16* __restrict__ wih_hi,   // [3H][H] layer slice
    const __hip_bfloat16* __restrict__ whh_hi,   // [3H][H]
    const __hip_bfloat16* __restrict__ whh_lo,   // [3H][H]
    const float* __restrict__ bih,               // [3H]
    const float* __restrict__ bhh,               // [3H]
    int t) {
  const int g = blockIdx.x;
  const int tid = threadIdx.x;
  const int wave = tid >> 6;
  const int lane = tid & 63;
  const int l15 = lane & 15;
  const int quad = lane >> 4;
  const int koff = quad * 8;          // A/B frag: k = quad*8 + j, j in [0,8)
  const int u = g * 16 + l15;         // this lane's unit column (n index)

  // A-operand rows (m = lane&15 within the wave's m-tile)
  const __hip_bfloat16* xrow = seq_in + (size_t)t * (NB * NH)
                               + (size_t)(wave * 16 + l15) * NH + koff;
  const __hip_bfloat16* hrow = h_in + (size_t)(wave * 16 + l15) * NH + koff;
  // B-operand rows: W[n][k], n = gate*H + u (contiguous in k)
  const __hip_bfloat16* wri = wih_hi + (size_t)u * NH + koff;
  const __hip_bfloat16* wzi = wih_hi + (size_t)(NH + u) * NH + koff;
  const __hip_bfloat16* wni = wih_hi + (size_t)(2 * NH + u) * NH + koff;
  const __hip_bfloat16* wra = whh_hi + (size_t)u * NH + koff;
  const __hip_bfloat16* wza = whh_hi + (size_t)(NH + u) * NH + koff;
  const __hip_bfloat16* wna = whh_hi + (size_t)(2 * NH + u) * NH + koff;
  const __hip_bfloat16* wrb = whh_lo + (size_t)u * NH + koff;
  const __hip_bfloat16* wzb = whh_lo + (size_t)(NH + u) * NH + koff;
  const __hip_bfloat16* wnb = whh_lo + (size_t)(2 * NH + u) * NH + koff;

  floatx4 z4 = {0.f, 0.f, 0.f, 0.f};
  floatx4 gir = z4, giz = z4, gin = z4;   // x @ Wih_hi
  floatx4 gar = z4, gaz = z4, gan = z4;   // h @ Whh_hi
  floatx4 gbr = z4, gbz = z4, gbn = z4;   // h @ Whh_lo

#pragma unroll 4
  for (int k = 0; k < NH; k += 32) {
    short8 ax = ld8(xrow + k);
    short8 ah = ld8(hrow + k);
    gir = __builtin_amdgcn_mfma_f32_16x16x32_bf16(ax, ld8(wri + k), gir, 0, 0, 0);
    giz = __builtin_amdgcn_mfma_f32_16x16x32_bf16(ax, ld8(wzi + k), giz, 0, 0, 0);
    gin = __builtin_amdgcn_mfma_f32_16x16x32_bf16(ax, ld8(wni + k), gin, 0, 0, 0);
    gar = __builtin_amdgcn_mfma_f32_16x16x32_bf16(ah, ld8(wra + k), gar, 0, 0, 0);
    gaz = __builtin_amdgcn_mfma_f32_16x16x32_bf16(ah, ld8(wza + k), gaz, 0, 0, 0);
    gan = __builtin_amdgcn_mfma_f32_16x16x32_bf16(ah, ld8(wna + k), gan, 0, 0, 0);
    gbr = __builtin_amdgcn_mfma_f32_16x16x32_bf16(ah, ld8(wrb + k), gbr, 0, 0, 0);
    gbz = __builtin_amdgcn_mfma_f32_16x16x32_bf16(ah, ld8(wzb + k), gbz, 0, 0, 0);
    gbn = __builtin_amdgcn_mfma_f32_16x16x32_bf16(ah, ld8(wnb + k), gbn, 0, 0, 0);
  }

  // biases (per unit column, shared across the 4 acc rows)
  const float bir = bih[u], biz = bih[NH + u], bin = bih[2 * NH + u];
  const float bhr = bhh[u], bhz = bhh[NH + u], bhn = bhh[2 * NH + u];

  // C/D layout (verified m89): row = quad*4 + reg, col = lane&15
#pragma unroll
  for (int r = 0; r < 4; ++r) {
    const int batch = wave * 16 + quad * 4 + r;
    const size_t idx = (size_t)batch * NH + u;
    float vgi_r = gir[r] + bir;
    float vgi_z = giz[r] + biz;
    float vgi_n = gin[r] + bin;
    float vgh_r = gar[r] + gbr[r] + bhr;
    float vgh_z = gaz[r] + gbz[r] + bhz;
    float vgh_n = gan[r] + gbn[r] + bhn;
    float rr = 1.f / (1.f + expf(-(vgi_r + vgh_r)));
    float zz = 1.f / (1.f + expf(-(vgi_z + vgh_z)));
    float nn = tanhf(vgi_n + rr * vgh_n);
    float hp = h_fp[idx];
    float hn = (1.f - zz) * nn + zz * hp;
    h_fp[idx] = hn;
    __hip_bfloat16 hb = __float2bfloat16(hn);
    h_out[idx] = hb;
    if (seq_out) seq_out[(size_t)t * (NB * NH) + idx] = hb;
  }
}

// ---------------- launch ----------------
extern "C" void kernel_launch(void* const* d_in, const int* in_sizes, int n_in,
                              void* d_out, int out_size, void* d_ws, size_t ws_size,
                              hipStream_t stream) {
  const float* x    = (const float*)d_in[0];  // [T,B,IN]
  const float* h0   = (const float*)d_in[1];  // [L,B,H]
  const float* w_ih = (const float*)d_in[2];  // [L,3H,IN]
  const float* w_hh = (const float*)d_in[3];  // [L,3H,H]
  const float* b_ih = (const float*)d_in[4];  // [L,3H]
  const float* b_hh = (const float*)d_in[5];  // [L,3H]
  float* out = (float*)d_out;                 // [L,B,H] = fp32 h master state

  char* ws = (char*)d_ws;
  size_t off = 0;
  const size_t wsz = (size_t)NL * N3H * NH * sizeof(__hip_bfloat16);  // 25.2 MB
  __hip_bfloat16* wih_hi = (__hip_bfloat16*)(ws + off); off += wsz;
  __hip_bfloat16* whh_hi = (__hip_bfloat16*)(ws + off); off += wsz;
  __hip_bfloat16* whh_lo = (__hip_bfloat16*)(ws + off); off += wsz;
  __hip_bfloat16* hbuf   = (__hip_bfloat16*)(ws + off);               // [2][B*H]
  off += (size_t)2 * NB * NH * sizeof(__hip_bfloat16);
  const size_t seq_sz = (size_t)NT * NB * NH * sizeof(__hip_bfloat16); // 67.1 MB
  __hip_bfloat16* seqA = (__hip_bfloat16*)(ws + off); off += seq_sz;
  __hip_bfloat16* seqB = (__hip_bfloat16*)(ws + off); off += seq_sz;
  (void)ws_size; (void)in_sizes; (void)n_in; (void)out_size;

  // prep
  {
    size_t n = (size_t)NL * N3H * NH;
    split_w_kernel<<<dim3((n + 255) / 256), dim3(256), 0, stream>>>(
        w_ih, w_hh, wih_hi, whh_hi, whh_lo);
  }
  {
    size_t n = (size_t)NT * NB * NH;
    split_x_kernel<<<dim3((n + 255) / 256), dim3(256), 0, stream>>>(x, seqA);
  }
  {
    size_t n = (size_t)NL * NB * NH;
    init_out_kernel<<<dim3((n + 255) / 256), dim3(256), 0, stream>>>(h0, out);
  }

  const size_t bh = (size_t)NB * NH;
  for (int l = 0; l < NL; ++l) {
    init_hbf_kernel<<<dim3((bh + 255) / 256), dim3(256), 0, stream>>>(
        h0 + (size_t)l * bh, hbuf);  // parity 0
    const __hip_bfloat16* sin = (l & 1) ? seqB : seqA;
    __hip_bfloat16* sout = (l == NL - 1) ? (__hip_bfloat16*)nullptr
                                         : ((l & 1) ? seqA : seqB);
    const __hip_bfloat16* wih_l = wih_hi + (size_t)l * N3H * NH;
    const __hip_bfloat16* whha_l = whh_hi + (size_t)l * N3H * NH;
    const __hip_bfloat16* whhb_l = whh_lo + (size_t)l * N3H * NH;
    const float* bih_l = b_ih + (size_t)l * N3H;
    const float* bhh_l = b_hh + (size_t)l * N3H;
    float* hfp_l = out + (size_t)l * bh;
    for (int t = 0; t < NT; ++t) {
      gru_step_kernel<<<dim3(64), dim3(256), 0, stream>>>(
          sin, sout, hbuf + (size_t)(t & 1) * bh, hbuf + (size_t)((t + 1) & 1) * bh,
          hfp_l, wih_l, whha_l, whhb_l, bih_l, bhh_l, t);
    }
  }
}

// Round 2
// 48541.473 us; speedup vs baseline: 1.7898x; 1.7898x over previous
//
#include <hip/hip_runtime.h>
#include <hip/hip_bf16.h>

#define NL 4
#define NB 64
#define NT 512
#define NH 1024
#define N3H 3072
#define FSTRIDE 4   // ints per flag slot (16 B padding)

typedef __attribute__((ext_vector_type(8))) short short8;
typedef __attribute__((ext_vector_type(4))) float floatx4;

__device__ __forceinline__ short8 ld8(const __hip_bfloat16* p) {
  return *(const short8*)p;
}

// ---------------- prep kernels ----------------

// w_ih -> bf16 ; w_hh -> bf16 hi (all rows) + bf16 lo (n-gate rows only)
__global__ void conv_w_kernel(const float* __restrict__ w_ih,
                              const float* __restrict__ w_hh,
                              __hip_bfloat16* __restrict__ wih_b,
                              __hip_bfloat16* __restrict__ whh_hi,
                              __hip_bfloat16* __restrict__ whh_lo_n) {
  size_t i = (size_t)blockIdx.x * 256 + threadIdx.x;
  if (i >= (size_t)NL * N3H * NH) return;
  wih_b[i] = __float2bfloat16(w_ih[i]);
  float v = w_hh[i];
  __hip_bfloat16 hi = __float2bfloat16(v);
  whh_hi[i] = hi;
  size_t l = i / ((size_t)N3H * NH);
  size_t rem = i - l * ((size_t)N3H * NH);
  size_t row = rem / NH;
  if (row >= (size_t)2 * NH) {
    size_t k = rem - row * NH;
    whh_lo_n[(l * NH + (row - 2 * NH)) * NH + k] =
        __float2bfloat16(v - __bfloat162float(hi));
  }
}

__global__ void conv_x_kernel(const float* __restrict__ x,
                              __hip_bfloat16* __restrict__ xb) {
  size_t i = (size_t)blockIdx.x * 256 + threadIdx.x;
  if (i >= (size_t)NT * NB * NH) return;
  xb[i] = __float2bfloat16(x[i]);
}

// h0 -> d_out (fp32 master) ; zero the flag array
__global__ void init_out_kernel(const float* __restrict__ h0,
                                float* __restrict__ out,
                                int* __restrict__ flags) {
  size_t i = (size_t)blockIdx.x * 256 + threadIdx.x;
  if (i < (size_t)4 * 64 * FSTRIDE) flags[i] = 0;
  if (i >= (size_t)NL * NB * NH) return;
  out[i] = h0[i];
}

__global__ void init_hbf_kernel(const float* __restrict__ h0_layer,
                                __hip_bfloat16* __restrict__ hb) {
  size_t i = (size_t)blockIdx.x * 256 + threadIdx.x;
  if (i >= (size_t)NB * NH) return;
  hb[i] = __float2bfloat16(h0_layer[i]);
}

// ---------------- gi GEMM: C[M][3072] = A[M][1024] @ W[3072][1024]^T + bih --
// 128x128 tile, BK=32, LDS-staged, 256 thr (4 waves, 2x2 of 64x64)
__global__ __launch_bounds__(256) void gemm_gi_kernel(
    const __hip_bfloat16* __restrict__ A,
    const __hip_bfloat16* __restrict__ Wb,
    const float* __restrict__ bih,
    float* __restrict__ C) {
  __shared__ short lA[128 * 32];
  __shared__ short lB[128 * 32];
  const int tid = threadIdx.x;
  const int wave = tid >> 6, lane = tid & 63;
  const int l15 = lane & 15, quad = lane >> 4;
  const int m0 = blockIdx.x * 128;
  const int n0 = blockIdx.y * 128;
  const int wm = (wave >> 1) * 64, wn = (wave & 1) * 64;

  const int r1 = tid >> 2, c1 = (tid & 3) * 8;  // staging map (i = tid)
  const __hip_bfloat16* Arow0 = A + (size_t)(m0 + r1) * NH + c1;
  const __hip_bfloat16* Arow1 = A + (size_t)(m0 + r1 + 64) * NH + c1;
  const __hip_bfloat16* Brow0 = Wb + (size_t)(n0 + r1) * NH + c1;
  const __hip_bfloat16* Brow1 = Wb + (size_t)(n0 + r1 + 64) * NH + c1;

  floatx4 z4 = {0.f, 0.f, 0.f, 0.f};
  floatx4 acc[4][4];
#pragma unroll
  for (int mi = 0; mi < 4; ++mi)
#pragma unroll
    for (int ni = 0; ni < 4; ++ni) acc[mi][ni] = z4;

  for (int kt = 0; kt < 32; ++kt) {
    const int ko = kt * 32;
    short8 a0 = ld8(Arow0 + ko), a1 = ld8(Arow1 + ko);
    short8 b0 = ld8(Brow0 + ko), b1 = ld8(Brow1 + ko);
    __syncthreads();
    *(short8*)(lA + tid * 8) = a0;
    *(short8*)(lA + (tid + 256) * 8) = a1;
    *(short8*)(lB + tid * 8) = b0;
    *(short8*)(lB + (tid + 256) * 8) = b1;
    __syncthreads();
    short8 af[4], bf[4];
#pragma unroll
    for (int mi = 0; mi < 4; ++mi)
      af[mi] = *(short8*)(lA + (wm + mi * 16 + l15) * 32 + quad * 8);
#pragma unroll
    for (int ni = 0; ni < 4; ++ni)
      bf[ni] = *(short8*)(lB + (wn + ni * 16 + l15) * 32 + quad * 8);
#pragma unroll
    for (int mi = 0; mi < 4; ++mi)
#pragma unroll
      for (int ni = 0; ni < 4; ++ni)
        acc[mi][ni] =
            __builtin_amdgcn_mfma_f32_16x16x32_bf16(af[mi], bf[ni], acc[mi][ni], 0, 0, 0);
  }

  const int crow = m0 + wm + quad * 4;
#pragma unroll
  for (int ni = 0; ni < 4; ++ni) {
    const int col = n0 + wn + ni * 16 + l15;
    const float bias = bih[col];
#pragma unroll
    for (int mi = 0; mi < 4; ++mi)
#pragma unroll
      for (int r = 0; r < 4; ++r)
        C[(size_t)(crow + mi * 16 + r) * N3H + col] = acc[mi][ni][r] + bias;
  }
}

// ---------------- recurrent chunk kernel ----------------
// 256 blocks x 64 thr. block = (batch-group w = bid>>6) x (unit-group g = bid&63).
// n-gate hi+lo weight frags in 64 KB LDS (frag order, conflict-free);
// r/z hi weights streamed from L2/LLC. Per-batch-group flag sync each step.
__global__ __launch_bounds__(64) void gru_persist_kernel(
    const __hip_bfloat16* __restrict__ whh_hi_l,  // [3072][1024]
    const __hip_bfloat16* __restrict__ whh_lo_l,  // [1024][1024] n-gate lo
    const float* __restrict__ gi_c,               // [TC][64][3072]
    const float* __restrict__ bhh_l,              // [3072]
    __hip_bfloat16* hbuf,                         // [2][64][1024] ping-pong
    __hip_bfloat16* seq_out,                      // [TC][64][1024] or null
    float* hfp,                                   // d_out + l*64*1024
    int* flags,                                   // [4*64*FSTRIDE]
    int s0, int nsteps) {
  const int lane = threadIdx.x;
  const int w = blockIdx.x >> 6;
  const int g = blockIdx.x & 63;
  const int l15 = lane & 15, quad = lane >> 4;
  const int u = g * 16 + l15;

  __shared__ short lds[32768];  // [2][32 kc][64 lane][8 bf16] = 64 KB

  // stage n-gate frags: lane's own B-frags for all kc (row u, k = kc*32+quad*8)
  {
    const __hip_bfloat16* srch = whh_hi_l + ((size_t)(2 * NH) + u) * NH + quad * 8;
    const __hip_bfloat16* srcl = whh_lo_l + (size_t)u * NH + quad * 8;
    short* dst = lds + lane * 8;
#pragma unroll 4
    for (int kc = 0; kc < 32; ++kc) {
      *(short8*)(dst + kc * 512) = ld8(srch + kc * 32);
      *(short8*)(dst + 16384 + kc * 512) = ld8(srcl + kc * 32);
    }
  }
  __syncthreads();

  const int bb = w * 16 + quad * 4;  // first batch row of this lane's acc
  float hreg[4];
#pragma unroll
  for (int r = 0; r < 4; ++r) hreg[r] = hfp[(size_t)(bb + r) * NH + u];

  const float bhr = bhh_l[u], bhz = bhh_l[NH + u], bhn = bhh_l[2 * NH + u];
  const __hip_bfloat16* wr = whh_hi_l + (size_t)u * NH + quad * 8;
  const __hip_bfloat16* wz = whh_hi_l + ((size_t)NH + u) * NH + quad * 8;

  int* myflag = flags + (w * 64 + lane) * FSTRIDE;  // producer this lane watches
  int* outflag = flags + (w * 64 + g) * FSTRIDE;    // this block's flag
  __hip_bfloat16* hb0 = hbuf;
  __hip_bfloat16* hb1 = hbuf + NB * NH;

  for (int s = s0; s < s0 + nsteps; ++s) {
    const int tc = s - s0;
    // gi prefetch (independent of flags -> issue before the spin)
    const float* gp = gi_c + ((size_t)tc * NB + bb) * N3H + u;
    float gi_r[4], gi_z[4], gi_n[4];
#pragma unroll
    for (int r = 0; r < 4; ++r) {
      gi_r[r] = gp[(size_t)r * N3H];
      gi_z[r] = gp[(size_t)r * N3H + NH];
      gi_n[r] = gp[(size_t)r * N3H + 2 * NH];
    }

    // wait until all 64 producers of this batch-group published state s
    while (__hip_atomic_load(myflag, __ATOMIC_ACQUIRE, __HIP_MEMORY_SCOPE_AGENT) < s)
      __builtin_amdgcn_s_sleep(2);

    const __hip_bfloat16* hrow =
        ((s & 1) ? hb1 : hb0) + (size_t)(w * 16 + l15) * NH + quad * 8;
    floatx4 accr = {0.f, 0.f, 0.f, 0.f}, accz = accr, accnh = accr, accnl = accr;
#pragma unroll 8
    for (int kc = 0; kc < 32; ++kc) {
      short8 ah = ld8(hrow + kc * 32);
      short8 brf = ld8(wr + kc * 32);
      short8 bzf = ld8(wz + kc * 32);
      short8 bnh = *(short8*)(lds + lane * 8 + kc * 512);
      short8 bnl = *(short8*)(lds + 16384 + lane * 8 + kc * 512);
      accr = __builtin_amdgcn_mfma_f32_16x16x32_bf16(ah, brf, accr, 0, 0, 0);
      accz = __builtin_amdgcn_mfma_f32_16x16x32_bf16(ah, bzf, accz, 0, 0, 0);
      accnh = __builtin_amdgcn_mfma_f32_16x16x32_bf16(ah, bnh, accnh, 0, 0, 0);
      accnl = __builtin_amdgcn_mfma_f32_16x16x32_bf16(ah, bnl, accnl, 0, 0, 0);
    }

    __hip_bfloat16* hout = (s & 1) ? hb0 : hb1;
#pragma unroll
    for (int r = 0; r < 4; ++r) {
      float ghr = accr[r] + bhr;
      float ghz = accz[r] + bhz;
      float ghn = accnh[r] + accnl[r] + bhn;
      float rr = 1.f / (1.f + __expf(-(gi_r[r] + ghr)));
      float zz = 1.f / (1.f + __expf(-(gi_z[r] + ghz)));
      float xt = gi_n[r] + rr * ghn;
      xt = fminf(fmaxf(xt, -15.f), 15.f);
      float e2 = __expf(2.f * xt);
      float nn = (e2 - 1.f) / (e2 + 1.f);
      float hn = (1.f - zz) * nn + zz * hreg[r];
      hreg[r] = hn;
      __hip_bfloat16 hb16 = __float2bfloat16(hn);
      size_t idx = (size_t)(bb + r) * NH + u;
      hout[idx] = hb16;
      if (seq_out) seq_out[(size_t)tc * (NB * NH) + idx] = hb16;
    }
    __threadfence();  // publish h (device scope) before raising the flag
    if (lane == 0)
      __hip_atomic_store(outflag, s + 1, __ATOMIC_RELEASE, __HIP_MEMORY_SCOPE_AGENT);
  }

#pragma unroll
  for (int r = 0; r < 4; ++r) hfp[(size_t)(bb + r) * NH + u] = hreg[r];
}

// ---------------- launch ----------------
extern "C" void kernel_launch(void* const* d_in, const int* in_sizes, int n_in,
                              void* d_out, int out_size, void* d_ws, size_t ws_size,
                              hipStream_t stream) {
  const float* x = (const float*)d_in[0];
  const float* h0 = (const float*)d_in[1];
  const float* w_ih = (const float*)d_in[2];
  const float* w_hh = (const float*)d_in[3];
  const float* b_ih = (const float*)d_in[4];
  const float* b_hh = (const float*)d_in[5];
  float* out = (float*)d_out;
  (void)in_sizes; (void)n_in; (void)out_size;

  char* ws = (char*)d_ws;
  size_t off = 0;
  const size_t wsz = (size_t)NL * N3H * NH * 2;  // 25.2 MB
  const size_t lsz = (size_t)NL * NH * NH * 2;   // 8.4 MB
  const size_t ssz = (size_t)NT * NB * NH * 2;   // 67.1 MB
  __hip_bfloat16* wih_b = (__hip_bfloat16*)(ws + off); off += wsz;
  __hip_bfloat16* whh_hi = (__hip_bfloat16*)(ws + off); off += wsz;
  __hip_bfloat16* whh_lo = (__hip_bfloat16*)(ws + off); off += lsz;
  __hip_bfloat16* seqA = (__hip_bfloat16*)(ws + off); off += ssz;
  __hip_bfloat16* seqB = (__hip_bfloat16*)(ws + off); off += ssz;
  __hip_bfloat16* hbuf = (__hip_bfloat16*)(ws + off); off += (size_t)2 * NB * NH * 2;
  int* flags = (int*)(ws + off); off += (size_t)4 * 64 * FSTRIDE * 4;
  off = (off + 255) & ~(size_t)255;
  float* gi_buf = (float*)(ws + off);

  // pick largest chunk length TC (divides 512) whose fp32 gi buffer fits
  long long avail = (long long)ws_size - (long long)off;
  int TC = 256;
  while (TC > 2 && (long long)TC * NB * N3H * 4 > avail) TC >>= 1;

  {
    size_t n = (size_t)NL * N3H * NH;
    conv_w_kernel<<<dim3((n + 255) / 256), dim3(256), 0, stream>>>(
        w_ih, w_hh, wih_b, whh_hi, whh_lo);
  }
  {
    size_t n = (size_t)NT * NB * NH;
    conv_x_kernel<<<dim3((n + 255) / 256), dim3(256), 0, stream>>>(x, seqA);
  }
  {
    size_t n = (size_t)NL * NB * NH;
    init_out_kernel<<<dim3((n + 255) / 256), dim3(256), 0, stream>>>(h0, out, flags);
  }

  const size_t bh = (size_t)NB * NH;
  const int nchunks = NT / TC;
  for (int l = 0; l < NL; ++l) {
    init_hbf_kernel<<<dim3((bh + 255) / 256), dim3(256), 0, stream>>>(
        h0 + (size_t)l * bh, hbuf);
    const __hip_bfloat16* cur = (l & 1) ? seqB : seqA;
    __hip_bfloat16* nxt = (l == NL - 1) ? (__hip_bfloat16*)nullptr
                                        : ((l & 1) ? seqA : seqB);
    const __hip_bfloat16* wih_l = wih_b + (size_t)l * N3H * NH;
    const __hip_bfloat16* whha_l = whh_hi + (size_t)l * N3H * NH;
    const __hip_bfloat16* whhb_l = whh_lo + (size_t)l * NH * NH;
    const float* bih_l = b_ih + (size_t)l * N3H;
    const float* bhh_l = b_hh + (size_t)l * N3H;
    float* hfp_l = out + (size_t)l * bh;
    for (int c = 0; c < nchunks; ++c) {
      const __hip_bfloat16* Ac = cur + (size_t)c * TC * bh;
      gemm_gi_kernel<<<dim3(TC * NB / 128, N3H / 128), dim3(256), 0, stream>>>(
          Ac, wih_l, bih_l, gi_buf);
      __hip_bfloat16* so = nxt ? nxt + (size_t)c * TC * bh : (__hip_bfloat16*)nullptr;
      gru_persist_kernel<<<dim3(256), dim3(64), 0, stream>>>(
          whha_l, whhb_l, gi_buf, bhh_l, hbuf, so, hfp_l, flags,
          l * NT + c * TC, TC);
    }
  }
}

// Round 3
// 28092.737 us; speedup vs baseline: 3.0926x; 1.7279x over previous
//
#include <hip/hip_runtime.h>
#include <hip/hip_bf16.h>

#define NL 4
#define NB 64
#define NT 512
#define NH 1024
#define N3H 3072
#define FSTRIDE 4   // ints per flag slot (16 B padding)

typedef __attribute__((ext_vector_type(8))) short short8;
typedef __attribute__((ext_vector_type(4))) float floatx4;

__device__ __forceinline__ short8 ld8(const __hip_bfloat16* p) {
  return *(const short8*)p;
}

// ---------------- prep kernels ----------------

// w_ih -> bf16 ; w_hh -> bf16 hi (all rows) + bf16 lo (n-gate rows only)
__global__ void conv_w_kernel(const float* __restrict__ w_ih,
                              const float* __restrict__ w_hh,
                              __hip_bfloat16* __restrict__ wih_b,
                              __hip_bfloat16* __restrict__ whh_hi,
                              __hip_bfloat16* __restrict__ whh_lo_n) {
  size_t i = (size_t)blockIdx.x * 256 + threadIdx.x;
  if (i >= (size_t)NL * N3H * NH) return;
  wih_b[i] = __float2bfloat16(w_ih[i]);
  float v = w_hh[i];
  __hip_bfloat16 hi = __float2bfloat16(v);
  whh_hi[i] = hi;
  size_t l = i / ((size_t)N3H * NH);
  size_t rem = i - l * ((size_t)N3H * NH);
  size_t row = rem / NH;
  if (row >= (size_t)2 * NH) {
    size_t k = rem - row * NH;
    whh_lo_n[(l * NH + (row - 2 * NH)) * NH + k] =
        __float2bfloat16(v - __bfloat162float(hi));
  }
}

__global__ void conv_x_kernel(const float* __restrict__ x,
                              __hip_bfloat16* __restrict__ xb) {
  size_t i = (size_t)blockIdx.x * 256 + threadIdx.x;
  if (i >= (size_t)NT * NB * NH) return;
  xb[i] = __float2bfloat16(x[i]);
}

// h0 -> d_out (fp32 master) ; zero the flag array
__global__ void init_out_kernel(const float* __restrict__ h0,
                                float* __restrict__ out,
                                int* __restrict__ flags) {
  size_t i = (size_t)blockIdx.x * 256 + threadIdx.x;
  if (i < (size_t)4 * 64 * FSTRIDE) flags[i] = 0;
  if (i >= (size_t)NL * NB * NH) return;
  out[i] = h0[i];
}

__global__ void init_hbf_kernel(const float* __restrict__ h0_layer,
                                __hip_bfloat16* __restrict__ hb) {
  size_t i = (size_t)blockIdx.x * 256 + threadIdx.x;
  if (i >= (size_t)NB * NH) return;
  hb[i] = __float2bfloat16(h0_layer[i]);
}

// ---------------- gi GEMM: C[M][3072] = A[M][1024] @ W[3072][1024]^T + bih --
__global__ __launch_bounds__(256) void gemm_gi_kernel(
    const __hip_bfloat16* __restrict__ A,
    const __hip_bfloat16* __restrict__ Wb,
    const float* __restrict__ bih,
    float* __restrict__ C) {
  __shared__ short lA[128 * 32];
  __shared__ short lB[128 * 32];
  const int tid = threadIdx.x;
  const int wave = tid >> 6, lane = tid & 63;
  const int l15 = lane & 15, quad = lane >> 4;
  const int m0 = blockIdx.x * 128;
  const int n0 = blockIdx.y * 128;
  const int wm = (wave >> 1) * 64, wn = (wave & 1) * 64;

  const int r1 = tid >> 2, c1 = (tid & 3) * 8;
  const __hip_bfloat16* Arow0 = A + (size_t)(m0 + r1) * NH + c1;
  const __hip_bfloat16* Arow1 = A + (size_t)(m0 + r1 + 64) * NH + c1;
  const __hip_bfloat16* Brow0 = Wb + (size_t)(n0 + r1) * NH + c1;
  const __hip_bfloat16* Brow1 = Wb + (size_t)(n0 + r1 + 64) * NH + c1;

  floatx4 z4 = {0.f, 0.f, 0.f, 0.f};
  floatx4 acc[4][4];
#pragma unroll
  for (int mi = 0; mi < 4; ++mi)
#pragma unroll
    for (int ni = 0; ni < 4; ++ni) acc[mi][ni] = z4;

  for (int kt = 0; kt < 32; ++kt) {
    const int ko = kt * 32;
    short8 a0 = ld8(Arow0 + ko), a1 = ld8(Arow1 + ko);
    short8 b0 = ld8(Brow0 + ko), b1 = ld8(Brow1 + ko);
    __syncthreads();
    *(short8*)(lA + tid * 8) = a0;
    *(short8*)(lA + (tid + 256) * 8) = a1;
    *(short8*)(lB + tid * 8) = b0;
    *(short8*)(lB + (tid + 256) * 8) = b1;
    __syncthreads();
    short8 af[4], bf[4];
#pragma unroll
    for (int mi = 0; mi < 4; ++mi)
      af[mi] = *(short8*)(lA + (wm + mi * 16 + l15) * 32 + quad * 8);
#pragma unroll
    for (int ni = 0; ni < 4; ++ni)
      bf[ni] = *(short8*)(lB + (wn + ni * 16 + l15) * 32 + quad * 8);
#pragma unroll
    for (int mi = 0; mi < 4; ++mi)
#pragma unroll
      for (int ni = 0; ni < 4; ++ni)
        acc[mi][ni] =
            __builtin_amdgcn_mfma_f32_16x16x32_bf16(af[mi], bf[ni], acc[mi][ni], 0, 0, 0);
  }

  const int crow = m0 + wm + quad * 4;
#pragma unroll
  for (int ni = 0; ni < 4; ++ni) {
    const int col = n0 + wn + ni * 16 + l15;
    const float bias = bih[col];
#pragma unroll
    for (int mi = 0; mi < 4; ++mi)
#pragma unroll
      for (int r = 0; r < 4; ++r)
        C[(size_t)(crow + mi * 16 + r) * N3H + col] = acc[mi][ni][r] + bias;
  }
}

// ---------------- recurrent chunk kernel ----------------
// Fence-free cross-block sync: h exchanged via sc0/sc1 write-through stores +
// cache-bypass loads (always-fresh at the LLC coherence point). Flags are
// RELAXED agent atomics -> no buffer_inv / buffer_wbl2 cache maintenance,
// L2 stays warm with the streamed r/z weights across all steps.
__global__ __launch_bounds__(64) void gru_persist_kernel(
    const __hip_bfloat16* __restrict__ whh_hi_l,  // [3072][1024]
    const __hip_bfloat16* __restrict__ whh_lo_l,  // [1024][1024] n-gate lo
    const float* __restrict__ gi_c,               // [TC][64][3072]
    const float* __restrict__ bhh_l,              // [3072]
    __hip_bfloat16* hbuf,                         // [2][64][1024] ping-pong
    __hip_bfloat16* seq_out,                      // [TC][64][1024] or null
    float* hfp,                                   // d_out + l*64*1024
    int* flags,                                   // [4*64*FSTRIDE]
    int s0, int nsteps) {
  const int lane = threadIdx.x;
  const int w = blockIdx.x >> 6;
  const int g = blockIdx.x & 63;
  const int l15 = lane & 15, quad = lane >> 4;
  const int u = g * 16 + l15;

  __shared__ short lds[32768];  // [2][32 kc][64 lane][8 bf16] = 64 KB

  // stage n-gate frags (hi+lo) in fragment order: conflict-free ds_read_b128
  {
    const __hip_bfloat16* srch = whh_hi_l + ((size_t)(2 * NH) + u) * NH + quad * 8;
    const __hip_bfloat16* srcl = whh_lo_l + (size_t)u * NH + quad * 8;
    short* dst = lds + lane * 8;
#pragma unroll 4
    for (int kc = 0; kc < 32; ++kc) {
      *(short8*)(dst + kc * 512) = ld8(srch + kc * 32);
      *(short8*)(dst + 16384 + kc * 512) = ld8(srcl + kc * 32);
    }
  }
  __syncthreads();

  const int bb = w * 16 + quad * 4;  // first batch row of this lane's acc
  float hreg[4];
#pragma unroll
  for (int r = 0; r < 4; ++r) hreg[r] = hfp[(size_t)(bb + r) * NH + u];

  const float bhr = bhh_l[u], bhz = bhh_l[NH + u], bhn = bhh_l[2 * NH + u];
  const __hip_bfloat16* wr = whh_hi_l + (size_t)u * NH + quad * 8;
  const __hip_bfloat16* wz = whh_hi_l + ((size_t)NH + u) * NH + quad * 8;

  int* myflag = flags + (w * 64 + lane) * FSTRIDE;  // producer this lane watches
  int* outflag = flags + (w * 64 + g) * FSTRIDE;    // this block's flag
  __hip_bfloat16* hb0 = hbuf;
  __hip_bfloat16* hb1 = hbuf + NB * NH;

  for (int s = s0; s < s0 + nsteps; ++s) {
    const int tc = s - s0;
    // gi prefetch (independent of the flag -> can be in flight during spin)
    const float* gp = gi_c + ((size_t)tc * NB + bb) * N3H + u;
    float gi_r[4], gi_z[4], gi_n[4];
#pragma unroll
    for (int r = 0; r < 4; ++r) {
      gi_r[r] = gp[(size_t)r * N3H];
      gi_z[r] = gp[(size_t)r * N3H + NH];
      gi_n[r] = gp[(size_t)r * N3H + 2 * NH];
    }

    // wait until all 64 producers of this batch-group published state s
    while (__hip_atomic_load(myflag, __ATOMIC_RELAXED, __HIP_MEMORY_SCOPE_AGENT) < s)
      __builtin_amdgcn_s_sleep(1);

    // h fragments: cache-bypass loads (sc0 sc1 -> read the LLC, never stale)
    const __hip_bfloat16* hbase =
        ((s & 1) ? hb1 : hb0) + (size_t)(w * 16 + l15) * NH + quad * 8;
    short8 hf[32];
#pragma unroll
    for (int kc = 0; kc < 32; ++kc)
      asm volatile("global_load_dwordx4 %0, %1, off sc0 sc1"
                   : "=v"(hf[kc]) : "v"(hbase + kc * 32));
    // tie the loaded regs to a vmcnt(0) so no MFMA consumes them early
#pragma unroll
    for (int g8 = 0; g8 < 32; g8 += 8)
      asm volatile("s_waitcnt vmcnt(0)"
                   : "+v"(hf[g8]), "+v"(hf[g8 + 1]), "+v"(hf[g8 + 2]),
                     "+v"(hf[g8 + 3]), "+v"(hf[g8 + 4]), "+v"(hf[g8 + 5]),
                     "+v"(hf[g8 + 6]), "+v"(hf[g8 + 7])
                   :: "memory");

    floatx4 accr = {0.f, 0.f, 0.f, 0.f}, accz = accr, accnh = accr, accnl = accr;
#pragma unroll 8
    for (int kc = 0; kc < 32; ++kc) {
      short8 ah = hf[kc];
      short8 brf = ld8(wr + kc * 32);
      short8 bzf = ld8(wz + kc * 32);
      short8 bnh = *(short8*)(lds + lane * 8 + kc * 512);
      short8 bnl = *(short8*)(lds + 16384 + lane * 8 + kc * 512);
      accr = __builtin_amdgcn_mfma_f32_16x16x32_bf16(ah, brf, accr, 0, 0, 0);
      accz = __builtin_amdgcn_mfma_f32_16x16x32_bf16(ah, bzf, accz, 0, 0, 0);
      accnh = __builtin_amdgcn_mfma_f32_16x16x32_bf16(ah, bnh, accnh, 0, 0, 0);
      accnl = __builtin_amdgcn_mfma_f32_16x16x32_bf16(ah, bnl, accnl, 0, 0, 0);
    }

    __hip_bfloat16* hout = (s & 1) ? hb0 : hb1;
#pragma unroll
    for (int r = 0; r < 4; ++r) {
      float ghr = accr[r] + bhr;
      float ghz = accz[r] + bhz;
      float ghn = accnh[r] + accnl[r] + bhn;
      float rr = 1.f / (1.f + __expf(-(gi_r[r] + ghr)));
      float zz = 1.f / (1.f + __expf(-(gi_z[r] + ghz)));
      float xt = gi_n[r] + rr * ghn;
      xt = fminf(fmaxf(xt, -15.f), 15.f);
      float e2 = __expf(2.f * xt);
      float nn = (e2 - 1.f) / (e2 + 1.f);
      float hn = (1.f - zz) * nn + zz * hreg[r];
      hreg[r] = hn;
      __hip_bfloat16 hb16 = __float2bfloat16(hn);
      size_t idx = (size_t)(bb + r) * NH + u;
      // write-through to the LLC (no dirty L2 line -> vmcnt(0) is a full release)
      unsigned int v32 = (unsigned int)__builtin_bit_cast(unsigned short, hb16);
      asm volatile("global_store_short %0, %1, off sc0 sc1"
                   :: "v"(hout + idx), "v"(v32) : "memory");
      if (seq_out) seq_out[(size_t)tc * (NB * NH) + idx] = hb16;
    }
    asm volatile("s_waitcnt vmcnt(0)" ::: "memory");  // h visible at LLC
    if (lane == 0)
      __hip_atomic_store(outflag, s + 1, __ATOMIC_RELAXED, __HIP_MEMORY_SCOPE_AGENT);
  }

#pragma unroll
  for (int r = 0; r < 4; ++r) hfp[(size_t)(bb + r) * NH + u] = hreg[r];
}

// ---------------- launch ----------------
extern "C" void kernel_launch(void* const* d_in, const int* in_sizes, int n_in,
                              void* d_out, int out_size, void* d_ws, size_t ws_size,
                              hipStream_t stream) {
  const float* x = (const float*)d_in[0];
  const float* h0 = (const float*)d_in[1];
  const float* w_ih = (const float*)d_in[2];
  const float* w_hh = (const float*)d_in[3];
  const float* b_ih = (const float*)d_in[4];
  const float* b_hh = (const float*)d_in[5];
  float* out = (float*)d_out;
  (void)in_sizes; (void)n_in; (void)out_size;

  char* ws = (char*)d_ws;
  size_t off = 0;
  const size_t wsz = (size_t)NL * N3H * NH * 2;  // 25.2 MB
  const size_t lsz = (size_t)NL * NH * NH * 2;   // 8.4 MB
  const size_t ssz = (size_t)NT * NB * NH * 2;   // 67.1 MB
  __hip_bfloat16* wih_b = (__hip_bfloat16*)(ws + off); off += wsz;
  __hip_bfloat16* whh_hi = (__hip_bfloat16*)(ws + off); off += wsz;
  __hip_bfloat16* whh_lo = (__hip_bfloat16*)(ws + off); off += lsz;
  __hip_bfloat16* seqA = (__hip_bfloat16*)(ws + off); off += ssz;
  __hip_bfloat16* seqB = (__hip_bfloat16*)(ws + off); off += ssz;
  __hip_bfloat16* hbuf = (__hip_bfloat16*)(ws + off); off += (size_t)2 * NB * NH * 2;
  int* flags = (int*)(ws + off); off += (size_t)4 * 64 * FSTRIDE * 4;
  off = (off + 255) & ~(size_t)255;
  float* gi_buf = (float*)(ws + off);

  // pick largest chunk length TC (divides 512) whose fp32 gi buffer fits
  long long avail = (long long)ws_size - (long long)off;
  int TC = 256;
  while (TC > 2 && (long long)TC * NB * N3H * 4 > avail) TC >>= 1;

  {
    size_t n = (size_t)NL * N3H * NH;
    conv_w_kernel<<<dim3((n + 255) / 256), dim3(256), 0, stream>>>(
        w_ih, w_hh, wih_b, whh_hi, whh_lo);
  }
  {
    size_t n = (size_t)NT * NB * NH;
    conv_x_kernel<<<dim3((n + 255) / 256), dim3(256), 0, stream>>>(x, seqA);
  }
  {
    size_t n = (size_t)NL * NB * NH;
    init_out_kernel<<<dim3((n + 255) / 256), dim3(256), 0, stream>>>(h0, out, flags);
  }

  const size_t bh = (size_t)NB * NH;
  const int nchunks = NT / TC;
  for (int l = 0; l < NL; ++l) {
    init_hbf_kernel<<<dim3((bh + 255) / 256), dim3(256), 0, stream>>>(
        h0 + (size_t)l * bh, hbuf);
    const __hip_bfloat16* cur = (l & 1) ? seqB : seqA;
    __hip_bfloat16* nxt = (l == NL - 1) ? (__hip_bfloat16*)nullptr
                                        : ((l & 1) ? seqA : seqB);
    const __hip_bfloat16* wih_l = wih_b + (size_t)l * N3H * NH;
    const __hip_bfloat16* whha_l = whh_hi + (size_t)l * N3H * NH;
    const __hip_bfloat16* whhb_l = whh_lo + (size_t)l * NH * NH;
    const float* bih_l = b_ih + (size_t)l * N3H;
    const float* bhh_l = b_hh + (size_t)l * N3H;
    float* hfp_l = out + (size_t)l * bh;
    for (int c = 0; c < nchunks; ++c) {
      const __hip_bfloat16* Ac = cur + (size_t)c * TC * bh;
      gemm_gi_kernel<<<dim3(TC * NB / 128, N3H / 128), dim3(256), 0, stream>>>(
          Ac, wih_l, bih_l, gi_buf);
      __hip_bfloat16* so = nxt ? nxt + (size_t)c * TC * bh : (__hip_bfloat16*)nullptr;
      gru_persist_kernel<<<dim3(256), dim3(64), 0, stream>>>(
          whha_l, whhb_l, gi_buf, bhh_l, hbuf, so, hfp_l, flags,
          l * NT + c * TC, TC);
    }
  }
}